// Round 1
// baseline (281.073 us; speedup 1.0000x reference)
//
#include <hip/hip_runtime.h>

#define NROWS 262144
#define NCOLS 128
#define NBLOCKS 4096
#define TPB 256
#define WAVES_PER_BLOCK (TPB / 64)

// Each wave processes a pair of adjacent rows: lanes 0-31 -> row 2p,
// lanes 32-63 -> row 2p+1. Each lane loads float4 of x and of target
// (16B/lane, fully coalesced: the wave touches 2 contiguous rows = 1KiB).
__global__ __launch_bounds__(TPB) void biased_loss_partial(
    const float* __restrict__ x, const float* __restrict__ t,
    float* __restrict__ partial)
{
    const int lane = threadIdx.x & 63;
    const int waveInBlock = threadIdx.x >> 6;
    const int globalWave = blockIdx.x * WAVES_PER_BLOCK + waveInBlock;
    const int totalWaves = gridDim.x * WAVES_PER_BLOCK;

    const int half = lane >> 5;   // which row of the pair
    const int sub  = lane & 31;   // lane within the 32-lane half

    float acc = 0.0f;

    const int npairs = NROWS / 2;
    for (int p = globalWave; p < npairs; p += totalWaves) {
        const int row = p * 2 + half;
        const size_t base = (size_t)row * NCOLS + (size_t)sub * 4;
        const float4 xv = *(const float4*)(x + base);
        const float4 tv = *(const float4*)(t + base);

        // per-lane argmax over 4 elements, first-occurrence tie-break
        int c = sub * 4;
        float bv = xv.x; int bi = c;
        if (xv.y > bv) { bv = xv.y; bi = c + 1; }
        if (xv.z > bv) { bv = xv.z; bi = c + 2; }
        if (xv.w > bv) { bv = xv.w; bi = c + 3; }

        // butterfly argmax across the 32-lane half.
        // off <= 16 flips only low 5 bits of the lane id, so the shuffle
        // stays inside this half even with width 64.
        #pragma unroll
        for (int off = 16; off > 0; off >>= 1) {
            float ov = __shfl_xor(bv, off, 64);
            int   oi = __shfl_xor(bi, off, 64);
            if (ov > bv || (ov == bv && oi < bi)) { bv = ov; bi = oi; }
        }
        // all 32 lanes of the half now agree on (bv, bi)

        // broadcast target[row][0] from the half's first lane
        float t0 = __shfl(tv.x, half << 5, 64);
        const bool cond = (bi > 0) && (t0 == 0.0f);

        float c0 = fabsf(xv.x * tv.x);
        float c1 = fabsf(xv.y * tv.y);
        float c2 = fabsf(xv.z * tv.z);
        float c3 = fabsf(xv.w * tv.w);

        float s;
        if (cond) {
            // only the argmax column survives
            s = (c     == bi ? c0 : 0.0f)
              + (c + 1 == bi ? c1 : 0.0f)
              + (c + 2 == bi ? c2 : 0.0f)
              + (c + 3 == bi ? c3 : 0.0f);
        } else {
            s = c0 + c1 + c2 + c3;
        }
        acc += s;
    }

    // full-wave sum (both halves together — we only need the total)
    #pragma unroll
    for (int off = 32; off > 0; off >>= 1)
        acc += __shfl_xor(acc, off, 64);

    __shared__ float smem[WAVES_PER_BLOCK];
    if (lane == 0) smem[waveInBlock] = acc;
    __syncthreads();
    if (threadIdx.x == 0) {
        float b = 0.0f;
        #pragma unroll
        for (int w = 0; w < WAVES_PER_BLOCK; ++w) b += smem[w];
        partial[blockIdx.x] = b;
    }
}

__global__ __launch_bounds__(256) void reduce_partials(
    const float* __restrict__ partial, float* __restrict__ out, int n)
{
    float acc = 0.0f;
    for (int i = threadIdx.x; i < n; i += 256) acc += partial[i];
    #pragma unroll
    for (int off = 32; off > 0; off >>= 1)
        acc += __shfl_xor(acc, off, 64);
    __shared__ float smem[4];
    const int lane = threadIdx.x & 63, w = threadIdx.x >> 6;
    if (lane == 0) smem[w] = acc;
    __syncthreads();
    if (threadIdx.x == 0) {
        float s = smem[0] + smem[1] + smem[2] + smem[3];
        out[0] = s / (float)((size_t)NROWS * (size_t)NCOLS);
    }
}

extern "C" void kernel_launch(void* const* d_in, const int* in_sizes, int n_in,
                              void* d_out, int out_size, void* d_ws, size_t ws_size,
                              hipStream_t stream) {
    const float* x = (const float*)d_in[0];
    const float* t = (const float*)d_in[1];
    float* partial = (float*)d_ws;  // NBLOCKS * 4 bytes = 16 KiB scratch

    biased_loss_partial<<<NBLOCKS, TPB, 0, stream>>>(x, t, partial);
    reduce_partials<<<1, 256, 0, stream>>>(partial, (float*)d_out, NBLOCKS);
}

// Round 2
// 279.540 us; speedup vs baseline: 1.0055x; 1.0055x over previous
//
#include <hip/hip_runtime.h>

#define NROWS 262144
#define NCOLS 128
#define TPB 256
#define WPB (TPB / 64)
#define NBLOCKS 2048
#define NWAVES (NBLOCKS * WPB)          // 8192
#define ROWS_PER_GROUP 8
#define NGROUPS (NROWS / ROWS_PER_GROUP) // 32768 -> 4 groups per wave

// 8 rows per wave: lanes [8g..8g+7] own row g of the group; each lane holds
// 16 elements (4x float4 at column offsets s*4 + {0,32,64,96}).
__global__ __launch_bounds__(TPB) void biased_loss_partial(
    const float* __restrict__ x, const float* __restrict__ t,
    float* __restrict__ partial)
{
    const int lane = threadIdx.x & 63;
    const int waveInBlock = threadIdx.x >> 6;
    const int gw = blockIdx.x * WPB + waveInBlock;
    const int g = lane >> 3;   // row within the 8-row group
    const int s = lane & 7;    // lane within the row

    float acc = 0.0f;

    #pragma unroll 2
    for (int grp = gw; grp < NGROUPS; grp += NWAVES) {
        const int row = grp * ROWS_PER_GROUP + g;
        const float* xr = x + (size_t)row * NCOLS + (size_t)s * 4;
        const float* tr = t + (size_t)row * NCOLS + (size_t)s * 4;

        // issue all 8 loads before any compute
        float4 xv[4], tv[4];
        #pragma unroll
        for (int j = 0; j < 4; ++j) xv[j] = *(const float4*)(xr + j * 32);
        #pragma unroll
        for (int j = 0; j < 4; ++j) tv[j] = *(const float4*)(tr + j * 32);

        // unpack in increasing-column order: col = 32*j + 4*s + k
        float xe[16], ce[16];
        #pragma unroll
        for (int j = 0; j < 4; ++j) {
            xe[4*j+0] = xv[j].x; xe[4*j+1] = xv[j].y;
            xe[4*j+2] = xv[j].z; xe[4*j+3] = xv[j].w;
            ce[4*j+0] = fabsf(xv[j].x * tv[j].x);
            ce[4*j+1] = fabsf(xv[j].y * tv[j].y);
            ce[4*j+2] = fabsf(xv[j].z * tv[j].z);
            ce[4*j+3] = fabsf(xv[j].w * tv[j].w);
        }

        // lane-local argmax tree over 16 elems, first-occurrence tie-break:
        // combining (lo, hi) in index order with strict '>' keeps lower index.
        float bvv[16]; int bii[16]; float bcc[16];
        #pragma unroll
        for (int e = 0; e < 16; ++e) {
            bvv[e] = xe[e];
            bii[e] = 32 * (e >> 2) + 4 * s + (e & 3);
            bcc[e] = ce[e];
        }
        #pragma unroll
        for (int w = 8; w >= 1; w >>= 1) {
            #pragma unroll
            for (int e = 0; e < 16; ++e) {
                if (e < w) {
                    bool take = bvv[e + w] > bvv[e];
                    bvv[e] = take ? bvv[e + w] : bvv[e];
                    bii[e] = take ? bii[e + w] : bii[e];
                    bcc[e] = take ? bcc[e + w] : bcc[e];
                }
            }
        }
        float bv = bvv[0]; int bi = bii[0]; float bc = bcc[0];

        // cross-lane argmax over the 8 lanes of this row (xor of low 3 bits
        // stays inside the 8-lane group)
        #pragma unroll
        for (int off = 4; off > 0; off >>= 1) {
            float ov = __shfl_xor(bv, off, 64);
            int   oi = __shfl_xor(bi, off, 64);
            float oc = __shfl_xor(bc, off, 64);
            bool take = (ov > bv) || (ov == bv && oi < bi);
            bv = take ? ov : bv;
            bi = take ? oi : bi;
            bc = take ? oc : bc;
        }
        // all 8 lanes of the row agree on (bv, bi, bc)

        // target[row][0] lives in lane s==0, tv[0].x
        float t0 = __shfl(tv[0].x, g << 3, 64);
        const bool cond = (bi > 0) && (t0 == 0.0f);

        // per-lane full-row partial sum (tree add for ILP)
        #pragma unroll
        for (int w = 8; w >= 1; w >>= 1) {
            #pragma unroll
            for (int e = 0; e < 16; ++e)
                if (e < w) ce[e] += ce[e + w];
        }
        float psum = ce[0];

        // masked case: only the argmax element survives; charge it once
        // (to lane s==0 of the row).
        acc += cond ? (s == 0 ? bc : 0.0f) : psum;
    }

    // full-wave sum
    #pragma unroll
    for (int off = 32; off > 0; off >>= 1)
        acc += __shfl_xor(acc, off, 64);

    __shared__ float smem[WPB];
    if (lane == 0) smem[waveInBlock] = acc;
    __syncthreads();
    if (threadIdx.x == 0) {
        float b = 0.0f;
        #pragma unroll
        for (int w = 0; w < WPB; ++w) b += smem[w];
        partial[blockIdx.x] = b;
    }
}

__global__ __launch_bounds__(256) void reduce_partials(
    const float* __restrict__ partial, float* __restrict__ out, int n)
{
    float acc = 0.0f;
    for (int i = threadIdx.x; i < n; i += 256) acc += partial[i];
    #pragma unroll
    for (int off = 32; off > 0; off >>= 1)
        acc += __shfl_xor(acc, off, 64);
    __shared__ float smem[4];
    const int lane = threadIdx.x & 63, w = threadIdx.x >> 6;
    if (lane == 0) smem[w] = acc;
    __syncthreads();
    if (threadIdx.x == 0) {
        float s = smem[0] + smem[1] + smem[2] + smem[3];
        out[0] = s / (float)((size_t)NROWS * (size_t)NCOLS);
    }
}

extern "C" void kernel_launch(void* const* d_in, const int* in_sizes, int n_in,
                              void* d_out, int out_size, void* d_ws, size_t ws_size,
                              hipStream_t stream) {
    const float* x = (const float*)d_in[0];
    const float* t = (const float*)d_in[1];
    float* partial = (float*)d_ws;  // NBLOCKS * 4 B = 8 KiB scratch

    biased_loss_partial<<<NBLOCKS, TPB, 0, stream>>>(x, t, partial);
    reduce_partials<<<1, 256, 0, stream>>>(partial, (float*)d_out, NBLOCKS);
}

// Round 3
// 276.040 us; speedup vs baseline: 1.0182x; 1.0127x over previous
//
#include <hip/hip_runtime.h>

#define NROWS 262144
#define NCOLS 128
#define TPB 256
#define WPB (TPB / 64)
#define NBLOCKS 2048                     // 8 blocks/CU * 256 CUs: one full round
#define NWAVES (NBLOCKS * WPB)           // 8192 waves
#define NPAIRS (NROWS / 2)               // 131072
#define U 4                              // pairs batched per load phase
#define NBATCH (NPAIRS / (NWAVES * U))   // 4 batches per wave

// R1 layout: lanes 0-31 -> row 2p, lanes 32-63 -> row 2p+1; each lane loads
// one float4 of x and t (wave covers 1KB contiguous per array per pair).
// U=4 pairs' loads are issued back-to-back (8 loads in flight) before any
// processing; the 4 shuffle chains are independent and interleave.
__global__ __launch_bounds__(TPB, 8) void biased_loss_partial(
    const float* __restrict__ x, const float* __restrict__ t,
    float* __restrict__ partial)
{
    const int lane = threadIdx.x & 63;
    const int waveInBlock = threadIdx.x >> 6;
    const int gw = blockIdx.x * WPB + waveInBlock;
    const int half = lane >> 5;
    const int sub  = lane & 31;

    float acc = 0.0f;

    #pragma unroll
    for (int b = 0; b < NBATCH; ++b) {
        const int pbase = (b * NWAVES + gw) * U;   // 4 consecutive pairs

        float4 xv[U], tv[U];
        #pragma unroll
        for (int u = 0; u < U; ++u) {
            const size_t base =
                (size_t)(2 * (pbase + u) + half) * NCOLS + (size_t)sub * 4;
            xv[u] = *(const float4*)(x + base);
            tv[u] = *(const float4*)(t + base);
        }

        #pragma unroll
        for (int u = 0; u < U; ++u) {
            const int c = sub * 4;
            float bv = xv[u].x; int bi = c;
            if (xv[u].y > bv) { bv = xv[u].y; bi = c + 1; }
            if (xv[u].z > bv) { bv = xv[u].z; bi = c + 2; }
            if (xv[u].w > bv) { bv = xv[u].w; bi = c + 3; }

            // butterfly argmax across the 32-lane half (off<=16 stays in half)
            #pragma unroll
            for (int off = 16; off > 0; off >>= 1) {
                float ov = __shfl_xor(bv, off, 64);
                int   oi = __shfl_xor(bi, off, 64);
                if (ov > bv || (ov == bv && oi < bi)) { bv = ov; bi = oi; }
            }

            float t0 = __shfl(tv[u].x, half << 5, 64);
            const bool cond = (bi > 0) && (t0 == 0.0f);

            float c0 = fabsf(xv[u].x * tv[u].x);
            float c1 = fabsf(xv[u].y * tv[u].y);
            float c2 = fabsf(xv[u].z * tv[u].z);
            float c3 = fabsf(xv[u].w * tv[u].w);

            float s;
            if (cond) {
                s = (c     == bi ? c0 : 0.0f)
                  + (c + 1 == bi ? c1 : 0.0f)
                  + (c + 2 == bi ? c2 : 0.0f)
                  + (c + 3 == bi ? c3 : 0.0f);
            } else {
                s = (c0 + c1) + (c2 + c3);
            }
            acc += s;
        }
    }

    // full-wave sum
    #pragma unroll
    for (int off = 32; off > 0; off >>= 1)
        acc += __shfl_xor(acc, off, 64);

    __shared__ float smem[WPB];
    if (lane == 0) smem[waveInBlock] = acc;
    __syncthreads();
    if (threadIdx.x == 0) {
        float bsum = 0.0f;
        #pragma unroll
        for (int w = 0; w < WPB; ++w) bsum += smem[w];
        partial[blockIdx.x] = bsum;
    }
}

__global__ __launch_bounds__(256) void reduce_partials(
    const float* __restrict__ partial, float* __restrict__ out, int n)
{
    float acc = 0.0f;
    for (int i = threadIdx.x; i < n; i += 256) acc += partial[i];
    #pragma unroll
    for (int off = 32; off > 0; off >>= 1)
        acc += __shfl_xor(acc, off, 64);
    __shared__ float smem[4];
    const int lane = threadIdx.x & 63, w = threadIdx.x >> 6;
    if (lane == 0) smem[w] = acc;
    __syncthreads();
    if (threadIdx.x == 0) {
        float s = smem[0] + smem[1] + smem[2] + smem[3];
        out[0] = s / (float)((size_t)NROWS * (size_t)NCOLS);
    }
}

extern "C" void kernel_launch(void* const* d_in, const int* in_sizes, int n_in,
                              void* d_out, int out_size, void* d_ws, size_t ws_size,
                              hipStream_t stream) {
    const float* x = (const float*)d_in[0];
    const float* t = (const float*)d_in[1];
    float* partial = (float*)d_ws;  // NBLOCKS * 4 B = 8 KiB scratch

    biased_loss_partial<<<NBLOCKS, TPB, 0, stream>>>(x, t, partial);
    reduce_partials<<<1, 256, 0, stream>>>(partial, (float*)d_out, NBLOCKS);
}